// Round 14
// baseline (893.458 us; speedup 1.0000x reference)
//
#include <hip/hip_runtime.h>
#include <hip/hip_bf16.h>
#include <math.h>

#define NNODES 50000
#define NEDGES 800000
#define NGRAPH 64
#define FIN 128
#define HC 256     // H * HID
#define NHEAD 4
#define NOUT 10
#define ETOT (NEDGES + NNODES)   // edges + self-loops
#define NB196 ((NNODES + 255) / 256)   // 196 scan blocks / sort buckets
#define BUCKET_MAX 5376                 // 15 sigma above mean bucket size (4352)

// Channel permutation σ (within each 64-channel head block):
//   stored p = (c & ~63) | ((c&15)<<2) | ((c>>4)&3)   [actual c -> stored p]
// Hb (fp8) and Ab (bf16) live in σ-layout; w2b/w3b K-dims σ-permuted at
// conversion; bias/Wl loads re-indexed; es/ed epilogue uses fp32 acc directly.

typedef unsigned short u16;
typedef unsigned char u8;
typedef __attribute__((ext_vector_type(8))) short short8;
typedef __attribute__((ext_vector_type(4))) float f32x4;
typedef __attribute__((ext_vector_type(2))) float f32x2;

__device__ inline u16 f2b(float f) {
    union { float f; unsigned u; } v; v.f = f;
    unsigned r = v.u + 0x7FFF + ((v.u >> 16) & 1);   // RNE (finite values)
    return (u16)(r >> 16);
}
__device__ inline float b2f(u16 u) {
    union { unsigned u; float f; } v; v.u = ((unsigned)u) << 16; return v.f;
}

__device__ inline void gload_lds16(const void* g, void* l) {
    __builtin_amdgcn_global_load_lds(
        (const __attribute__((address_space(1))) unsigned*)g,
        (__attribute__((address_space(3))) unsigned*)l, 16, 0, 0);
}

// ---------------- prep: fused bf16 conversions + edge degree histogram ----------------
// w2b/w3b are written with σ-permuted K (inner) dimension.

#define CS0 (NNODES * FIN)   // 6,400,000
#define CS1 (HC * FIN)       // 32,768
#define CS2 (HC * HC)        // 65,536
#define NBCONV (((CS0 + CS1 + 2 * CS2) / 4 + 255) / 256)   // 6410
#define NBDEG ((ETOT + 255) / 256)                          // 3321

__global__ void prep_kernel(const float* __restrict__ x, const float* __restrict__ W1,
                            const float* __restrict__ W2, const float* __restrict__ W3,
                            u16* __restrict__ xb, u16* __restrict__ w1b,
                            u16* __restrict__ w2b, u16* __restrict__ w3b,
                            const int* __restrict__ ei, int* __restrict__ deg) {
    int b = blockIdx.x;
    if (b < NBCONV) {
        long i = (long)(b * 256 + threadIdx.x) * 4;
        if (i < CS0) {
            float4 v = *(const float4*)(x + i);
            ushort4 o;
            o.x = f2b(v.x); o.y = f2b(v.y); o.z = f2b(v.z); o.w = f2b(v.w);
            *(ushort4*)(xb + i) = o;
        } else if (i < CS0 + CS1) {
            long off = i - CS0;
            float4 v = *(const float4*)(W1 + off);
            ushort4 o;
            o.x = f2b(v.x); o.y = f2b(v.y); o.z = f2b(v.z); o.w = f2b(v.w);
            *(ushort4*)(w1b + off) = o;
        } else if (i < CS0 + CS1 + 2 * CS2) {
            const float* src; u16* dst; long off;
            if (i < CS0 + CS1 + CS2) { src = W2; dst = w2b; off = i - CS0 - CS1; }
            else                     { src = W3; dst = w3b; off = i - CS0 - CS1 - CS2; }
            float4 v = *(const float4*)(src + off);
            int row = (int)(off >> 8), col = (int)(off & 255);
            float vv[4] = {v.x, v.y, v.z, v.w};
            #pragma unroll
            for (int k = 0; k < 4; ++k) {
                int c = col + k;
                int pp = (c & ~63) | ((c & 15) << 2) | ((c >> 4) & 3);
                dst[row * 256 + pp] = f2b(vv[k]);
            }
        }
    } else {
        int e = (b - NBCONV) * 256 + threadIdx.x;
        if (e >= ETOT) return;
        int dstn = (e < NEDGES) ? ei[NEDGES + e] : (e - NEDGES);
        atomicAdd(&deg[dstn], 1);
    }
}

// ---------------- hierarchical scan (block-partial off + scanned bsum) ----------------

__global__ __launch_bounds__(256) void scan1_kernel(const int* __restrict__ deg,
                                                    int* __restrict__ off,
                                                    int* __restrict__ bsum) {
    int tid = threadIdx.x, lane = tid & 63, wid = tid >> 6;
    int i = blockIdx.x * 256 + tid;
    __shared__ int ws[4];
    int v = (i < NNODES) ? deg[i] : 0;
    int x = v;
    #pragma unroll
    for (int o = 1; o < 64; o <<= 1) {
        int t = __shfl_up(x, o);
        if (lane >= o) x += t;
    }
    if (lane == 63) ws[wid] = x;
    __syncthreads();
    if (tid < 4) {
        int w = ws[tid];
        #pragma unroll
        for (int o = 1; o < 4; o <<= 1) {
            int t = __shfl_up(w, o, 4);
            if ((tid & 3) >= o) w += t;
        }
        ws[tid] = w;
    }
    __syncthreads();
    int wexcl = wid ? ws[wid - 1] : 0;
    if (i <= NNODES) off[i] = x - v + wexcl;
    if (tid == 0) bsum[blockIdx.x] = ws[3];
}

__global__ __launch_bounds__(256) void scan2_kernel(int* __restrict__ bsum,
                                                    const int* __restrict__ batch,
                                                    int* __restrict__ goff) {
    int tid = threadIdx.x, lane = tid & 63, wid = tid >> 6;
    __shared__ int ws[4];
    int v = (tid < NB196) ? bsum[tid] : 0;
    int x = v;
    #pragma unroll
    for (int o = 1; o < 64; o <<= 1) {
        int t = __shfl_up(x, o);
        if (lane >= o) x += t;
    }
    if (lane == 63) ws[wid] = x;
    __syncthreads();
    if (tid < 4) {
        int w = ws[tid];
        #pragma unroll
        for (int o = 1; o < 4; o <<= 1) {
            int t = __shfl_up(w, o, 4);
            if ((tid & 3) >= o) w += t;
        }
        ws[tid] = w;
    }
    __syncthreads();
    int wexcl = wid ? ws[wid - 1] : 0;
    if (tid <= NB196) bsum[tid] = x - v + wexcl;   // bsum[NB196] = grand total
    if (tid <= NGRAPH) {
        int g = tid, lo = 0, hi = NNODES;
        while (lo < hi) {
            int mid = (lo + hi) >> 1;
            if (batch[mid] < g) lo = mid + 1; else hi = mid;
        }
        goff[g] = lo;
    }
}

// ---------------- two-pass edge sort (replaces random 4B scatter) ----------------
// Pass 1: bucket by dst>>8; sequential writes per bucket (L2-resident lines).
// Packed u32: src (16b, NNODES<65536) | local-dst (8b) << 16.

__global__ void scatter1_kernel(const int* __restrict__ ei, const int* __restrict__ bsum,
                                int* __restrict__ bcur, unsigned* __restrict__ tmp) {
    int e = blockIdx.x * blockDim.x + threadIdx.x;
    if (e >= ETOT) return;
    int src, dst;
    if (e < NEDGES) { src = ei[e]; dst = ei[NEDGES + e]; }
    else            { src = dst = e - NEDGES; }
    int bucket = dst >> 8;
    int pos = bsum[bucket] + atomicAdd(&bcur[bucket], 1);
    tmp[pos] = (unsigned)src | ((unsigned)(dst & 255) << 16);
}

// Pass 2: one block per bucket; rank per-dst via LDS counters (off[] is the
// within-bucket exclusive prefix), scatter into LDS, copy out coalesced.
// Defensive clamp on the LDS index (overflow probability ~0, but a clamp is
// cheaper than a container crash).
__global__ __launch_bounds__(256) void scatter2_kernel(const unsigned* __restrict__ tmp,
                                                       const int* __restrict__ off,
                                                       const int* __restrict__ bsum,
                                                       int* __restrict__ ssrc) {
    __shared__ int cnt[256];
    __shared__ int ldss[BUCKET_MAX];
    int b = blockIdx.x;
    int tid = threadIdx.x;
    int s = bsum[b], e2 = bsum[b + 1];
    int total = e2 - s;
    if (total > BUCKET_MAX) total = BUCKET_MAX;
    cnt[tid] = 0;
    __syncthreads();
    const int* offb = off + b * 256;
    for (int i = s + tid; i < e2; i += 256) {
        unsigned pk = tmp[i];
        int src = (int)(pk & 0xFFFFu);
        int ld = (int)(pk >> 16);
        int rank = atomicAdd(&cnt[ld], 1);
        int idx = offb[ld] + rank;
        if (idx < BUCKET_MAX) ldss[idx] = src;
    }
    __syncthreads();
    for (int i = tid; i < total; i += 256)
        ssrc[s + i] = ldss[i];
}

// ---------------- bf16 MFMA GEMM + fused e_src/e_dst epilogue ----------------
// C[N,256] = A[N,K] @ B[256,K]^T. 128x128 tile, 4 waves, BK=32, unpadded LDS +
// global_load_lds(16B), single buffer (best of R6-R9). C is stored in fp8
// e4m3 σ-layout (aggregate is the ONLY consumer of C since the es/ed fusion).

#define TBM 128
#define TBN 128
#define TBK 32

__global__ __launch_bounds__(256) void gemm_mfma(const u16* __restrict__ A,
                                                 const u16* __restrict__ B,
                                                 u8* __restrict__ C, int K,
                                                 const float* __restrict__ asrc,
                                                 const float* __restrict__ adst,
                                                 float* __restrict__ es,
                                                 float* __restrict__ ed) {
    __shared__ u16 Als[TBM * TBK];   // 8 KB
    __shared__ u16 Bls[TBN * TBK];   // 8 KB
    int tid = threadIdx.x;
    int wave = tid >> 6, lane = tid & 63;
    int brow = blockIdx.x * TBM, bcol = blockIdx.y * TBN;
    int m_base = (wave >> 1) * 64, n_base = (wave & 1) * 64;
    int r0 = tid >> 2, kc = (tid & 3) * 8;
    int lquad = lane >> 4, l16 = lane & 15;

    f32x4 acc[4][4] = {};

    const u16* ga0 = A + (size_t)(brow + r0) * K + kc;
    const u16* ga1 = A + (size_t)(brow + 64 + r0) * K + kc;
    const u16* gb0 = B + (size_t)(bcol + r0) * K + kc;
    const u16* gb1 = B + (size_t)(bcol + 64 + r0) * K + kc;
    u16* la0 = &Als[r0 * TBK + kc];          // byte offset == tid*16 (wave-contiguous)
    u16* la1 = &Als[(64 + r0) * TBK + kc];
    u16* lb0 = &Bls[r0 * TBK + kc];
    u16* lb1 = &Bls[(64 + r0) * TBK + kc];

    for (int k0 = 0; k0 < K; k0 += TBK) {
        __syncthreads();
        gload_lds16(ga0 + k0, la0);
        gload_lds16(ga1 + k0, la1);
        gload_lds16(gb0 + k0, lb0);
        gload_lds16(gb1 + k0, lb1);
        __syncthreads();
        short8 fa[4], fb[4];
        #pragma unroll
        for (int i = 0; i < 4; ++i) {
            fa[i] = *(const short8*)(&Als[(m_base + i * 16 + l16) * TBK + lquad * 8]);
            fb[i] = *(const short8*)(&Bls[(n_base + i * 16 + l16) * TBK + lquad * 8]);
        }
        #pragma unroll
        for (int i = 0; i < 4; ++i)
            #pragma unroll
            for (int j = 0; j < 4; ++j)
                acc[i][j] = __builtin_amdgcn_mfma_f32_16x16x32_bf16(fa[i], fb[j], acc[i][j], 0, 0, 0);
    }

    // fp8 σ-layout C store: stored bytes n_base+l16*4+{0..3} = acc[i][0..3][r]
    #pragma unroll
    for (int i = 0; i < 4; ++i) {
        int rbase = brow + m_base + i * 16 + lquad * 4;
        #pragma unroll
        for (int r = 0; r < 4; ++r) {
            int row = rbase + r;
            if (row < NNODES) {
                int u = 0;
                u = __builtin_amdgcn_cvt_pk_fp8_f32(acc[i][0][r], acc[i][1][r], u, false);
                u = __builtin_amdgcn_cvt_pk_fp8_f32(acc[i][2][r], acc[i][3][r], u, true);
                *(int*)(C + (size_t)row * HC + bcol + n_base + l16 * 4) = u;
            }
        }
    }

    // fused attention-scalar epilogue (fp32 accumulators — full precision)
    int head = (bcol + n_base) >> 6;
    float asv[4], adv[4];
    #pragma unroll
    for (int j = 0; j < 4; ++j) {
        asv[j] = asrc[head * 64 + j * 16 + l16];
        adv[j] = adst[head * 64 + j * 16 + l16];
    }
    #pragma unroll
    for (int i = 0; i < 4; ++i) {
        #pragma unroll
        for (int r = 0; r < 4; ++r) {
            float ps = 0.f, pd = 0.f;
            #pragma unroll
            for (int j = 0; j < 4; ++j) {
                ps = fmaf(acc[i][j][r], asv[j], ps);
                pd = fmaf(acc[i][j][r], adv[j], pd);
            }
            #pragma unroll
            for (int o = 1; o < 16; o <<= 1) {
                ps += __shfl_xor(ps, o);
                pd += __shfl_xor(pd, o);
            }
            int row = brow + m_base + i * 16 + lquad * 4 + r;
            if (l16 == 0 && row < NNODES) {
                es[row * 4 + head] = ps;
                ed[row * 4 + head] = pd;
            }
        }
    }
}

// ---------------- aggregate: 4 dst/block, 16-edge chunks; fp8 h gather ----------------

__global__ __launch_bounds__(256) void aggregate_kernel(const u8* __restrict__ h,
                                                        const int* __restrict__ ssrc,
                                                        const int* __restrict__ off,
                                                        const int* __restrict__ bsum,
                                                        const float* __restrict__ es,
                                                        const float* __restrict__ ed,
                                                        const float* __restrict__ bias,
                                                        u16* __restrict__ out,
                                                        int apply_elu) {
    __shared__ int2 xch[4][4][17];   // [wave][head][16 edges + pad]
    const unsigned* h32 = (const unsigned*)h;   // 64 uints per row (σ-layout)
    int wid = threadIdx.x >> 6;
    int dst = blockIdx.x * 4 + wid;
    if (dst >= NNODES) return;
    int lane = threadIdx.x & 63;
    int head = lane >> 4;
    int j16 = lane & 15;
    int s = off[dst] + bsum[dst >> 8];
    int e = off[dst + 1] + bsum[(dst + 1) >> 8];
    float edh = ed[dst * 4 + head];
    int2* myslot = &xch[wid][head][0];

    float a0 = 0.f, a1 = 0.f, a2 = 0.f, a3 = 0.f, dpriv = 0.f;

    int base = s;
    for (; base + 16 <= e; base += 16) {
        int mysrc = ssrc[base + j16];
        float l = es[mysrc * 4 + head] + edh;
        l = fmaxf(l, 0.2f * l);
        float myex = __expf(l);
        dpriv += myex;
        myslot[j16] = make_int2(mysrc, __float_as_int(myex));
        #pragma unroll
        for (int j = 0; j < 16; ++j) {
            int2 pr = myslot[j];
            float exj = __int_as_float(pr.y);
            unsigned hv = h32[(unsigned)pr.x * 64 + lane];
            f32x2 lo = __builtin_amdgcn_cvt_pk_f32_fp8(hv, false);
            f32x2 hi = __builtin_amdgcn_cvt_pk_f32_fp8(hv, true);
            a0 += lo.x * exj;
            a1 += lo.y * exj;
            a2 += hi.x * exj;
            a3 += hi.y * exj;
        }
    }
    int cnt = e - base;
    if (cnt > 0) {
        int mysrc = 0; float myex = 0.f;
        if (j16 < cnt) {
            mysrc = ssrc[base + j16];
            float l = es[mysrc * 4 + head] + edh;
            l = fmaxf(l, 0.2f * l);
            myex = __expf(l);
            dpriv += myex;
        }
        myslot[j16] = make_int2(mysrc, __float_as_int(myex));
        for (int j = 0; j < cnt; ++j) {
            int2 pr = myslot[j];
            float exj = __int_as_float(pr.y);
            unsigned hv = h32[(unsigned)pr.x * 64 + lane];
            f32x2 lo = __builtin_amdgcn_cvt_pk_f32_fp8(hv, false);
            f32x2 hi = __builtin_amdgcn_cvt_pk_f32_fp8(hv, true);
            a0 += lo.x * exj;
            a1 += lo.y * exj;
            a2 += hi.x * exj;
            a3 += hi.y * exj;
        }
    }
    // denom: sum dpriv across the 16 lanes of this head group
    #pragma unroll
    for (int o = 1; o < 16; o <<= 1) dpriv += __shfl_xor(dpriv, o);
    float inv = 1.f / (dpriv + 1e-16f);
    // bias for stored positions lane*4+{0..3} = actual 64*(lane>>4)+(lane&15)+{0,16,32,48}
    int bbase = ((lane >> 4) << 6) | (lane & 15);
    float b0 = bias[bbase], b1 = bias[bbase + 16], b2 = bias[bbase + 32], b3 = bias[bbase + 48];
    float o0 = a0 * inv + b0;
    float o1 = a1 * inv + b1;
    float o2 = a2 * inv + b2;
    float o3 = a3 * inv + b3;
    if (apply_elu) {
        o0 = o0 > 0.f ? o0 : __expf(o0) - 1.f;
        o1 = o1 > 0.f ? o1 : __expf(o1) - 1.f;
        o2 = o2 > 0.f ? o2 : __expf(o2) - 1.f;
        o3 = o3 > 0.f ? o3 : __expf(o3) - 1.f;
    }
    ushort4 ov;
    ov.x = f2b(o0); ov.y = f2b(o1); ov.z = f2b(o2); ov.w = f2b(o3);
    *(ushort4*)(out + (size_t)dst * HC + lane * 4) = ov;
}

// ---------------- sliced mean-pool partials: block = (graph, 8 node-slices) ----------------

__global__ __launch_bounds__(256) void pool_kernel(const u16* __restrict__ hin,
                                                   const int* __restrict__ goff,
                                                   float* __restrict__ pp) {
    int g = blockIdx.x;
    int slice = blockIdx.y;            // 0..7
    int lane = threadIdx.x & 63;
    int wid = threadIdx.x >> 6;
    int s = goff[g], e = goff[g + 1];
    float a0 = 0.f, a1 = 0.f, a2 = 0.f, a3 = 0.f;
    for (int n = s + slice * 4 + wid; n < e; n += 32) {
        ushort4 hv = *(const ushort4*)(hin + (size_t)n * HC + lane * 4);
        a0 += b2f(hv.x); a1 += b2f(hv.y); a2 += b2f(hv.z); a3 += b2f(hv.w);
    }
    __shared__ float4 part[4][64];
    part[wid][lane] = make_float4(a0, a1, a2, a3);
    __syncthreads();
    if (wid == 0) {
        float4 p0 = part[0][lane], p1 = part[1][lane], p2 = part[2][lane], p3 = part[3][lane];
        float4 v = make_float4((p0.x + p1.x) + (p2.x + p3.x),
                               (p0.y + p1.y) + (p2.y + p3.y),
                               (p0.z + p1.z) + (p2.z + p3.z),
                               (p0.w + p1.w) + (p2.w + p3.w));
        *(float4*)(pp + ((size_t)(g * 8 + slice)) * HC + lane * 4) = v;
    }
}

// ---------------- final classifier: sum 8 slice-partials, mean, Wl dot ----------------

__global__ __launch_bounds__(64) void final_kernel(const float* __restrict__ pp,
                                                   const int* __restrict__ goff,
                                                   const float* __restrict__ Wl,
                                                   const float* __restrict__ bl,
                                                   float* __restrict__ out) {
    int g = blockIdx.x;
    int lane = threadIdx.x;
    float4 pv = make_float4(0.f, 0.f, 0.f, 0.f);
    #pragma unroll
    for (int sl = 0; sl < 8; ++sl) {
        float4 v = *(const float4*)(pp + ((size_t)(g * 8 + sl)) * HC + lane * 4);
        pv.x += v.x; pv.y += v.y; pv.z += v.z; pv.w += v.w;
    }
    float cntf = fmaxf((float)(goff[g + 1] - goff[g]), 1.f);
    float inv = 1.f / cntf;
    pv.x *= inv; pv.y *= inv; pv.z *= inv; pv.w *= inv;
    int wbase = ((lane >> 4) << 6) | (lane & 15);             // actual ch = wbase+{0,16,32,48}
    float acc[NOUT];
    #pragma unroll
    for (int o = 0; o < NOUT; ++o) {
        const float* w = Wl + o * HC + wbase;
        acc[o] = pv.x * w[0] + pv.y * w[16] + pv.z * w[32] + pv.w * w[48];
    }
    #pragma unroll
    for (int s = 32; s > 0; s >>= 1)
        #pragma unroll
        for (int o = 0; o < NOUT; ++o)
            acc[o] += __shfl_xor(acc[o], s);
    if (lane == 0) {
        #pragma unroll
        for (int o = 0; o < NOUT; ++o)
            out[g * NOUT + o] = acc[o] + bl[o];
    }
}

// ---------------- launch ----------------

extern "C" void kernel_launch(void* const* d_in, const int* in_sizes, int n_in,
                              void* d_out, int out_size, void* d_ws, size_t ws_size,
                              hipStream_t stream) {
    (void)in_sizes; (void)n_in; (void)out_size; (void)ws_size;
    const float* x   = (const float*)d_in[0];
    const int*   ei  = (const int*)d_in[1];
    const int*   bat = (const int*)d_in[2];
    const float* W1  = (const float*)d_in[3];
    const float* as1 = (const float*)d_in[4];
    const float* ad1 = (const float*)d_in[5];
    const float* b1  = (const float*)d_in[6];
    const float* W2  = (const float*)d_in[7];
    const float* as2 = (const float*)d_in[8];
    const float* ad2 = (const float*)d_in[9];
    const float* b2  = (const float*)d_in[10];
    const float* W3  = (const float*)d_in[11];
    const float* as3 = (const float*)d_in[12];
    const float* ad3 = (const float*)d_in[13];
    const float* b3  = (const float*)d_in[14];
    const float* Wl  = (const float*)d_in[15];
    const float* bl  = (const float*)d_in[16];
    float* out = (float*)d_out;

    char* ws = (char*)d_ws;
    size_t p = 0;
    auto alloc = [&](size_t bytes) {
        size_t a = p;
        p += (bytes + 255) & ~(size_t)255;
        return a;
    };
    int*      off  = (int*)(ws + alloc((NNODES + 1) * 4));
    int*      deg  = (int*)(ws + alloc((size_t)NNODES * 4));
    int*      bcur = (int*)(ws + alloc(256 * 4));
    int*      ssrc = (int*)(ws + alloc((size_t)ETOT * 4));
    unsigned* tmp  = (unsigned*)(ws + alloc((size_t)ETOT * 4));
    int*      bsum = (int*)(ws + alloc(256 * 4));
    float*    es   = (float*)(ws + alloc((size_t)NNODES * NHEAD * 4));
    float*    ed   = (float*)(ws + alloc((size_t)NNODES * NHEAD * 4));
    u16*      xb   = (u16*)(ws + alloc((size_t)NNODES * FIN * 2));
    u16*      w1b  = (u16*)(ws + alloc((size_t)HC * FIN * 2));
    u16*      w2b  = (u16*)(ws + alloc((size_t)HC * HC * 2));
    u16*      w3b  = (u16*)(ws + alloc((size_t)HC * HC * 2));
    u8*       Hb   = (u8*)(ws + alloc((size_t)NNODES * HC));       // fp8 e4m3, σ-layout
    u16*      Ab   = (u16*)(ws + alloc((size_t)NNODES * HC * 2));  // bf16, σ-layout
    float*    pp   = (float*)(ws + alloc((size_t)NGRAPH * 8 * HC * 4));   // pool partials
    int*      goff = (int*)(ws + alloc((size_t)(NGRAPH + 1) * 4));
    alloc(128 * 1024);   // slack: gemm A-tile over-read past row NNODES stays in d_ws

    // zero deg+bcur (contiguous)
    hipMemsetAsync(deg, 0, (size_t)((char*)ssrc - (char*)deg), stream);

    // conversions + degree histogram (one fused kernel)
    prep_kernel<<<NBCONV + NBDEG, 256, 0, stream>>>(x, W1, W2, W3, xb, w1b, w2b, w3b, ei, deg);

    // counting sort of edges by dst (two-pass, L2-friendly) — reused by all 3 layers
    scan1_kernel<<<NB196, 256, 0, stream>>>(deg, off, bsum);
    scan2_kernel<<<1, 256, 0, stream>>>(bsum, bat, goff);
    scatter1_kernel<<<NBDEG, 256, 0, stream>>>(ei, bsum, bcur, tmp);
    scatter2_kernel<<<NB196, 256, 0, stream>>>(tmp, off, bsum, ssrc);

    dim3 ggrid((NNODES + TBM - 1) / TBM, HC / TBN);
    int nblocks4 = (NNODES + 3) / 4;

    // layer 1
    gemm_mfma<<<ggrid, 256, 0, stream>>>(xb, w1b, Hb, FIN, as1, ad1, es, ed);
    aggregate_kernel<<<nblocks4, 256, 0, stream>>>(Hb, ssrc, off, bsum, es, ed, b1, Ab, 1);
    // layer 2
    gemm_mfma<<<ggrid, 256, 0, stream>>>(Ab, w2b, Hb, HC, as2, ad2, es, ed);
    aggregate_kernel<<<nblocks4, 256, 0, stream>>>(Hb, ssrc, off, bsum, es, ed, b2, Ab, 1);
    // layer 3
    gemm_mfma<<<ggrid, 256, 0, stream>>>(Ab, w3b, Hb, HC, as3, ad3, es, ed);
    aggregate_kernel<<<nblocks4, 256, 0, stream>>>(Hb, ssrc, off, bsum, es, ed, b3, Ab, 0);

    // pool + classify
    dim3 pgrid(NGRAPH, 8);
    pool_kernel<<<pgrid, 256, 0, stream>>>(Ab, goff, pp);
    final_kernel<<<NGRAPH, 64, 0, stream>>>(pp, goff, Wl, bl, out);
}

// Round 15
// 374.865 us; speedup vs baseline: 2.3834x; 2.3834x over previous
//
#include <hip/hip_runtime.h>
#include <hip/hip_bf16.h>
#include <math.h>

#define NNODES 50000
#define NEDGES 800000
#define NGRAPH 64
#define FIN 128
#define HC 256     // H * HID
#define NHEAD 4
#define NOUT 10
#define ETOT (NEDGES + NNODES)   // edges + self-loops
#define NB196 ((NNODES + 255) / 256)   // 196 scan blocks / sort buckets
#define BUCKET_MAX 5376                 // 15 sigma above mean bucket size (4352)
#define S1CHUNK 4096                    // edges per scatter1 block (16/thread)
#define NBS1 ((ETOT + S1CHUNK - 1) / S1CHUNK)   // 208

// Channel permutation σ (within each 64-channel head block):
//   stored p = (c & ~63) | ((c&15)<<2) | ((c>>4)&3)   [actual c -> stored p]
// Hb (fp8) and Ab (bf16) live in σ-layout; w2b/w3b K-dims σ-permuted at
// conversion; bias/Wl loads re-indexed; es/ed epilogue uses fp32 acc directly.

typedef unsigned short u16;
typedef unsigned char u8;
typedef __attribute__((ext_vector_type(8))) short short8;
typedef __attribute__((ext_vector_type(4))) float f32x4;
typedef __attribute__((ext_vector_type(2))) float f32x2;

__device__ inline u16 f2b(float f) {
    union { float f; unsigned u; } v; v.f = f;
    unsigned r = v.u + 0x7FFF + ((v.u >> 16) & 1);   // RNE (finite values)
    return (u16)(r >> 16);
}
__device__ inline float b2f(u16 u) {
    union { unsigned u; float f; } v; v.u = ((unsigned)u) << 16; return v.f;
}

__device__ inline void gload_lds16(const void* g, void* l) {
    __builtin_amdgcn_global_load_lds(
        (const __attribute__((address_space(1))) unsigned*)g,
        (__attribute__((address_space(3))) unsigned*)l, 16, 0, 0);
}

// ---------------- prep: fused bf16 conversions + edge degree histogram ----------------
// w2b/w3b are written with σ-permuted K (inner) dimension.

#define CS0 (NNODES * FIN)   // 6,400,000
#define CS1 (HC * FIN)       // 32,768
#define CS2 (HC * HC)        // 65,536
#define NBCONV (((CS0 + CS1 + 2 * CS2) / 4 + 255) / 256)   // 6410
#define NBDEG ((ETOT + 255) / 256)                          // 3321

__global__ void prep_kernel(const float* __restrict__ x, const float* __restrict__ W1,
                            const float* __restrict__ W2, const float* __restrict__ W3,
                            u16* __restrict__ xb, u16* __restrict__ w1b,
                            u16* __restrict__ w2b, u16* __restrict__ w3b,
                            const int* __restrict__ ei, int* __restrict__ deg) {
    int b = blockIdx.x;
    if (b < NBCONV) {
        long i = (long)(b * 256 + threadIdx.x) * 4;
        if (i < CS0) {
            float4 v = *(const float4*)(x + i);
            ushort4 o;
            o.x = f2b(v.x); o.y = f2b(v.y); o.z = f2b(v.z); o.w = f2b(v.w);
            *(ushort4*)(xb + i) = o;
        } else if (i < CS0 + CS1) {
            long off = i - CS0;
            float4 v = *(const float4*)(W1 + off);
            ushort4 o;
            o.x = f2b(v.x); o.y = f2b(v.y); o.z = f2b(v.z); o.w = f2b(v.w);
            *(ushort4*)(w1b + off) = o;
        } else if (i < CS0 + CS1 + 2 * CS2) {
            const float* src; u16* dst; long off;
            if (i < CS0 + CS1 + CS2) { src = W2; dst = w2b; off = i - CS0 - CS1; }
            else                     { src = W3; dst = w3b; off = i - CS0 - CS1 - CS2; }
            float4 v = *(const float4*)(src + off);
            int row = (int)(off >> 8), col = (int)(off & 255);
            float vv[4] = {v.x, v.y, v.z, v.w};
            #pragma unroll
            for (int k = 0; k < 4; ++k) {
                int c = col + k;
                int pp = (c & ~63) | ((c & 15) << 2) | ((c >> 4) & 3);
                dst[row * 256 + pp] = f2b(vv[k]);
            }
        }
    } else {
        int e = (b - NBCONV) * 256 + threadIdx.x;
        if (e >= ETOT) return;
        int dstn = (e < NEDGES) ? ei[NEDGES + e] : (e - NEDGES);
        atomicAdd(&deg[dstn], 1);
    }
}

// ---------------- hierarchical scan (block-partial off + scanned bsum) ----------------

__global__ __launch_bounds__(256) void scan1_kernel(const int* __restrict__ deg,
                                                    int* __restrict__ off,
                                                    int* __restrict__ bsum) {
    int tid = threadIdx.x, lane = tid & 63, wid = tid >> 6;
    int i = blockIdx.x * 256 + tid;
    __shared__ int ws[4];
    int v = (i < NNODES) ? deg[i] : 0;
    int x = v;
    #pragma unroll
    for (int o = 1; o < 64; o <<= 1) {
        int t = __shfl_up(x, o);
        if (lane >= o) x += t;
    }
    if (lane == 63) ws[wid] = x;
    __syncthreads();
    if (tid < 4) {
        int w = ws[tid];
        #pragma unroll
        for (int o = 1; o < 4; o <<= 1) {
            int t = __shfl_up(w, o, 4);
            if ((tid & 3) >= o) w += t;
        }
        ws[tid] = w;
    }
    __syncthreads();
    int wexcl = wid ? ws[wid - 1] : 0;
    if (i <= NNODES) off[i] = x - v + wexcl;
    if (tid == 0) bsum[blockIdx.x] = ws[3];
}

__global__ __launch_bounds__(256) void scan2_kernel(int* __restrict__ bsum,
                                                    const int* __restrict__ batch,
                                                    int* __restrict__ goff) {
    int tid = threadIdx.x, lane = tid & 63, wid = tid >> 6;
    __shared__ int ws[4];
    int v = (tid < NB196) ? bsum[tid] : 0;
    int x = v;
    #pragma unroll
    for (int o = 1; o < 64; o <<= 1) {
        int t = __shfl_up(x, o);
        if (lane >= o) x += t;
    }
    if (lane == 63) ws[wid] = x;
    __syncthreads();
    if (tid < 4) {
        int w = ws[tid];
        #pragma unroll
        for (int o = 1; o < 4; o <<= 1) {
            int t = __shfl_up(w, o, 4);
            if ((tid & 3) >= o) w += t;
        }
        ws[tid] = w;
    }
    __syncthreads();
    int wexcl = wid ? ws[wid - 1] : 0;
    if (tid <= NB196) bsum[tid] = x - v + wexcl;   // bsum[NB196] = grand total
    if (tid <= NGRAPH) {
        int g = tid, lo = 0, hi = NNODES;
        while (lo < hi) {
            int mid = (lo + hi) >> 1;
            if (batch[mid] < g) lo = mid + 1; else hi = mid;
        }
        goff[g] = lo;
    }
}

// ---------------- two-pass edge sort, pass 1 with BLOCK-AGGREGATED atomics ----------------
// R13's version did 850k global atomics on 196 counters (4300/address,
// serialized -> 532 us). Privatize: per-block LDS histogram + local ranks,
// ONE global atomicAdd per (block,bucket) = 41k atomics, 208/address.
// Packed u32: src (16b) | local-dst (8b) << 16.

__global__ __launch_bounds__(256) void scatter1_kernel(const int* __restrict__ ei,
                                                       const int* __restrict__ bsum,
                                                       int* __restrict__ bcur,
                                                       unsigned* __restrict__ tmp) {
    __shared__ int hist[NB196];
    __shared__ int basec[NB196];
    int tid = threadIdx.x;
    int e0 = blockIdx.x * S1CHUNK;
    for (int i = tid; i < NB196; i += 256) hist[i] = 0;
    __syncthreads();
    int bkt[16], rnk[16];
    unsigned pk[16];
    #pragma unroll
    for (int k = 0; k < 16; ++k) {
        int e = e0 + k * 256 + tid;
        bkt[k] = -1;
        if (e < ETOT) {
            int src, dst;
            if (e < NEDGES) { src = ei[e]; dst = ei[NEDGES + e]; }
            else            { src = dst = e - NEDGES; }
            int b = dst >> 8;
            bkt[k] = b;
            rnk[k] = atomicAdd(&hist[b], 1);
            pk[k] = (unsigned)src | ((unsigned)(dst & 255) << 16);
        }
    }
    __syncthreads();
    for (int i = tid; i < NB196; i += 256) {
        int h = hist[i];
        basec[i] = h ? atomicAdd(&bcur[i], h) : 0;
    }
    __syncthreads();
    #pragma unroll
    for (int k = 0; k < 16; ++k) {
        if (bkt[k] >= 0)
            tmp[bsum[bkt[k]] + basec[bkt[k]] + rnk[k]] = pk[k];
    }
}

// Pass 2: one block per bucket; rank per-dst via LDS counters (off[] is the
// within-bucket exclusive prefix), scatter into LDS, copy out coalesced.
__global__ __launch_bounds__(256) void scatter2_kernel(const unsigned* __restrict__ tmp,
                                                       const int* __restrict__ off,
                                                       const int* __restrict__ bsum,
                                                       int* __restrict__ ssrc) {
    __shared__ int cnt[256];
    __shared__ int ldss[BUCKET_MAX];
    int b = blockIdx.x;
    int tid = threadIdx.x;
    int s = bsum[b], e2 = bsum[b + 1];
    int total = e2 - s;
    if (total > BUCKET_MAX) total = BUCKET_MAX;
    cnt[tid] = 0;
    __syncthreads();
    const int* offb = off + b * 256;
    for (int i = s + tid; i < e2; i += 256) {
        unsigned pk = tmp[i];
        int src = (int)(pk & 0xFFFFu);
        int ld = (int)(pk >> 16);
        int rank = atomicAdd(&cnt[ld], 1);
        int idx = offb[ld] + rank;
        if (idx < BUCKET_MAX) ldss[idx] = src;
    }
    __syncthreads();
    for (int i = tid; i < total; i += 256)
        ssrc[s + i] = ldss[i];
}

// ---------------- bf16 MFMA GEMM + fused e_src/e_dst epilogue ----------------
// C[N,256] = A[N,K] @ B[256,K]^T. 128x128 tile, 4 waves, BK=32, unpadded LDS +
// global_load_lds(16B), single buffer (best of R6-R9). C is stored in fp8
// e4m3 σ-layout (aggregate is the ONLY consumer of C since the es/ed fusion).

#define TBM 128
#define TBN 128
#define TBK 32

__global__ __launch_bounds__(256) void gemm_mfma(const u16* __restrict__ A,
                                                 const u16* __restrict__ B,
                                                 u8* __restrict__ C, int K,
                                                 const float* __restrict__ asrc,
                                                 const float* __restrict__ adst,
                                                 float* __restrict__ es,
                                                 float* __restrict__ ed) {
    __shared__ u16 Als[TBM * TBK];   // 8 KB
    __shared__ u16 Bls[TBN * TBK];   // 8 KB
    int tid = threadIdx.x;
    int wave = tid >> 6, lane = tid & 63;
    int brow = blockIdx.x * TBM, bcol = blockIdx.y * TBN;
    int m_base = (wave >> 1) * 64, n_base = (wave & 1) * 64;
    int r0 = tid >> 2, kc = (tid & 3) * 8;
    int lquad = lane >> 4, l16 = lane & 15;

    f32x4 acc[4][4] = {};

    const u16* ga0 = A + (size_t)(brow + r0) * K + kc;
    const u16* ga1 = A + (size_t)(brow + 64 + r0) * K + kc;
    const u16* gb0 = B + (size_t)(bcol + r0) * K + kc;
    const u16* gb1 = B + (size_t)(bcol + 64 + r0) * K + kc;
    u16* la0 = &Als[r0 * TBK + kc];          // byte offset == tid*16 (wave-contiguous)
    u16* la1 = &Als[(64 + r0) * TBK + kc];
    u16* lb0 = &Bls[r0 * TBK + kc];
    u16* lb1 = &Bls[(64 + r0) * TBK + kc];

    for (int k0 = 0; k0 < K; k0 += TBK) {
        __syncthreads();
        gload_lds16(ga0 + k0, la0);
        gload_lds16(ga1 + k0, la1);
        gload_lds16(gb0 + k0, lb0);
        gload_lds16(gb1 + k0, lb1);
        __syncthreads();
        short8 fa[4], fb[4];
        #pragma unroll
        for (int i = 0; i < 4; ++i) {
            fa[i] = *(const short8*)(&Als[(m_base + i * 16 + l16) * TBK + lquad * 8]);
            fb[i] = *(const short8*)(&Bls[(n_base + i * 16 + l16) * TBK + lquad * 8]);
        }
        #pragma unroll
        for (int i = 0; i < 4; ++i)
            #pragma unroll
            for (int j = 0; j < 4; ++j)
                acc[i][j] = __builtin_amdgcn_mfma_f32_16x16x32_bf16(fa[i], fb[j], acc[i][j], 0, 0, 0);
    }

    // fp8 σ-layout C store: stored bytes n_base+l16*4+{0..3} = acc[i][0..3][r]
    #pragma unroll
    for (int i = 0; i < 4; ++i) {
        int rbase = brow + m_base + i * 16 + lquad * 4;
        #pragma unroll
        for (int r = 0; r < 4; ++r) {
            int row = rbase + r;
            if (row < NNODES) {
                int u = 0;
                u = __builtin_amdgcn_cvt_pk_fp8_f32(acc[i][0][r], acc[i][1][r], u, false);
                u = __builtin_amdgcn_cvt_pk_fp8_f32(acc[i][2][r], acc[i][3][r], u, true);
                *(int*)(C + (size_t)row * HC + bcol + n_base + l16 * 4) = u;
            }
        }
    }

    // fused attention-scalar epilogue (fp32 accumulators — full precision)
    int head = (bcol + n_base) >> 6;
    float asv[4], adv[4];
    #pragma unroll
    for (int j = 0; j < 4; ++j) {
        asv[j] = asrc[head * 64 + j * 16 + l16];
        adv[j] = adst[head * 64 + j * 16 + l16];
    }
    #pragma unroll
    for (int i = 0; i < 4; ++i) {
        #pragma unroll
        for (int r = 0; r < 4; ++r) {
            float ps = 0.f, pd = 0.f;
            #pragma unroll
            for (int j = 0; j < 4; ++j) {
                ps = fmaf(acc[i][j][r], asv[j], ps);
                pd = fmaf(acc[i][j][r], adv[j], pd);
            }
            #pragma unroll
            for (int o = 1; o < 16; o <<= 1) {
                ps += __shfl_xor(ps, o);
                pd += __shfl_xor(pd, o);
            }
            int row = brow + m_base + i * 16 + lquad * 4 + r;
            if (l16 == 0 && row < NNODES) {
                es[row * 4 + head] = ps;
                ed[row * 4 + head] = pd;
            }
        }
    }
}

// ---------------- aggregate: 4 dst/block, 16-edge chunks; fp8 h gather ----------------

__global__ __launch_bounds__(256) void aggregate_kernel(const u8* __restrict__ h,
                                                        const int* __restrict__ ssrc,
                                                        const int* __restrict__ off,
                                                        const int* __restrict__ bsum,
                                                        const float* __restrict__ es,
                                                        const float* __restrict__ ed,
                                                        const float* __restrict__ bias,
                                                        u16* __restrict__ out,
                                                        int apply_elu) {
    __shared__ int2 xch[4][4][17];   // [wave][head][16 edges + pad]
    const unsigned* h32 = (const unsigned*)h;   // 64 uints per row (σ-layout)
    int wid = threadIdx.x >> 6;
    int dst = blockIdx.x * 4 + wid;
    if (dst >= NNODES) return;
    int lane = threadIdx.x & 63;
    int head = lane >> 4;
    int j16 = lane & 15;
    int s = off[dst] + bsum[dst >> 8];
    int e = off[dst + 1] + bsum[(dst + 1) >> 8];
    float edh = ed[dst * 4 + head];
    int2* myslot = &xch[wid][head][0];

    float a0 = 0.f, a1 = 0.f, a2 = 0.f, a3 = 0.f, dpriv = 0.f;

    int base = s;
    for (; base + 16 <= e; base += 16) {
        int mysrc = ssrc[base + j16];
        float l = es[mysrc * 4 + head] + edh;
        l = fmaxf(l, 0.2f * l);
        float myex = __expf(l);
        dpriv += myex;
        myslot[j16] = make_int2(mysrc, __float_as_int(myex));
        #pragma unroll
        for (int j = 0; j < 16; ++j) {
            int2 pr = myslot[j];
            float exj = __int_as_float(pr.y);
            unsigned hv = h32[(unsigned)pr.x * 64 + lane];
            f32x2 lo = __builtin_amdgcn_cvt_pk_f32_fp8(hv, false);
            f32x2 hi = __builtin_amdgcn_cvt_pk_f32_fp8(hv, true);
            a0 += lo.x * exj;
            a1 += lo.y * exj;
            a2 += hi.x * exj;
            a3 += hi.y * exj;
        }
    }
    int cnt = e - base;
    if (cnt > 0) {
        int mysrc = 0; float myex = 0.f;
        if (j16 < cnt) {
            mysrc = ssrc[base + j16];
            float l = es[mysrc * 4 + head] + edh;
            l = fmaxf(l, 0.2f * l);
            myex = __expf(l);
            dpriv += myex;
        }
        myslot[j16] = make_int2(mysrc, __float_as_int(myex));
        for (int j = 0; j < cnt; ++j) {
            int2 pr = myslot[j];
            float exj = __int_as_float(pr.y);
            unsigned hv = h32[(unsigned)pr.x * 64 + lane];
            f32x2 lo = __builtin_amdgcn_cvt_pk_f32_fp8(hv, false);
            f32x2 hi = __builtin_amdgcn_cvt_pk_f32_fp8(hv, true);
            a0 += lo.x * exj;
            a1 += lo.y * exj;
            a2 += hi.x * exj;
            a3 += hi.y * exj;
        }
    }
    // denom: sum dpriv across the 16 lanes of this head group
    #pragma unroll
    for (int o = 1; o < 16; o <<= 1) dpriv += __shfl_xor(dpriv, o);
    float inv = 1.f / (dpriv + 1e-16f);
    // bias for stored positions lane*4+{0..3} = actual 64*(lane>>4)+(lane&15)+{0,16,32,48}
    int bbase = ((lane >> 4) << 6) | (lane & 15);
    float b0 = bias[bbase], b1 = bias[bbase + 16], b2 = bias[bbase + 32], b3 = bias[bbase + 48];
    float o0 = a0 * inv + b0;
    float o1 = a1 * inv + b1;
    float o2 = a2 * inv + b2;
    float o3 = a3 * inv + b3;
    if (apply_elu) {
        o0 = o0 > 0.f ? o0 : __expf(o0) - 1.f;
        o1 = o1 > 0.f ? o1 : __expf(o1) - 1.f;
        o2 = o2 > 0.f ? o2 : __expf(o2) - 1.f;
        o3 = o3 > 0.f ? o3 : __expf(o3) - 1.f;
    }
    ushort4 ov;
    ov.x = f2b(o0); ov.y = f2b(o1); ov.z = f2b(o2); ov.w = f2b(o3);
    *(ushort4*)(out + (size_t)dst * HC + lane * 4) = ov;
}

// ---------------- sliced mean-pool partials: block = (graph, 8 node-slices) ----------------

__global__ __launch_bounds__(256) void pool_kernel(const u16* __restrict__ hin,
                                                   const int* __restrict__ goff,
                                                   float* __restrict__ pp) {
    int g = blockIdx.x;
    int slice = blockIdx.y;            // 0..7
    int lane = threadIdx.x & 63;
    int wid = threadIdx.x >> 6;
    int s = goff[g], e = goff[g + 1];
    float a0 = 0.f, a1 = 0.f, a2 = 0.f, a3 = 0.f;
    for (int n = s + slice * 4 + wid; n < e; n += 32) {
        ushort4 hv = *(const ushort4*)(hin + (size_t)n * HC + lane * 4);
        a0 += b2f(hv.x); a1 += b2f(hv.y); a2 += b2f(hv.z); a3 += b2f(hv.w);
    }
    __shared__ float4 part[4][64];
    part[wid][lane] = make_float4(a0, a1, a2, a3);
    __syncthreads();
    if (wid == 0) {
        float4 p0 = part[0][lane], p1 = part[1][lane], p2 = part[2][lane], p3 = part[3][lane];
        float4 v = make_float4((p0.x + p1.x) + (p2.x + p3.x),
                               (p0.y + p1.y) + (p2.y + p3.y),
                               (p0.z + p1.z) + (p2.z + p3.z),
                               (p0.w + p1.w) + (p2.w + p3.w));
        *(float4*)(pp + ((size_t)(g * 8 + slice)) * HC + lane * 4) = v;
    }
}

// ---------------- final classifier: sum 8 slice-partials, mean, Wl dot ----------------

__global__ __launch_bounds__(64) void final_kernel(const float* __restrict__ pp,
                                                   const int* __restrict__ goff,
                                                   const float* __restrict__ Wl,
                                                   const float* __restrict__ bl,
                                                   float* __restrict__ out) {
    int g = blockIdx.x;
    int lane = threadIdx.x;
    float4 pv = make_float4(0.f, 0.f, 0.f, 0.f);
    #pragma unroll
    for (int sl = 0; sl < 8; ++sl) {
        float4 v = *(const float4*)(pp + ((size_t)(g * 8 + sl)) * HC + lane * 4);
        pv.x += v.x; pv.y += v.y; pv.z += v.z; pv.w += v.w;
    }
    float cntf = fmaxf((float)(goff[g + 1] - goff[g]), 1.f);
    float inv = 1.f / cntf;
    pv.x *= inv; pv.y *= inv; pv.z *= inv; pv.w *= inv;
    int wbase = ((lane >> 4) << 6) | (lane & 15);             // actual ch = wbase+{0,16,32,48}
    float acc[NOUT];
    #pragma unroll
    for (int o = 0; o < NOUT; ++o) {
        const float* w = Wl + o * HC + wbase;
        acc[o] = pv.x * w[0] + pv.y * w[16] + pv.z * w[32] + pv.w * w[48];
    }
    #pragma unroll
    for (int s = 32; s > 0; s >>= 1)
        #pragma unroll
        for (int o = 0; o < NOUT; ++o)
            acc[o] += __shfl_xor(acc[o], s);
    if (lane == 0) {
        #pragma unroll
        for (int o = 0; o < NOUT; ++o)
            out[g * NOUT + o] = acc[o] + bl[o];
    }
}

// ---------------- launch ----------------

extern "C" void kernel_launch(void* const* d_in, const int* in_sizes, int n_in,
                              void* d_out, int out_size, void* d_ws, size_t ws_size,
                              hipStream_t stream) {
    (void)in_sizes; (void)n_in; (void)out_size; (void)ws_size;
    const float* x   = (const float*)d_in[0];
    const int*   ei  = (const int*)d_in[1];
    const int*   bat = (const int*)d_in[2];
    const float* W1  = (const float*)d_in[3];
    const float* as1 = (const float*)d_in[4];
    const float* ad1 = (const float*)d_in[5];
    const float* b1  = (const float*)d_in[6];
    const float* W2  = (const float*)d_in[7];
    const float* as2 = (const float*)d_in[8];
    const float* ad2 = (const float*)d_in[9];
    const float* b2  = (const float*)d_in[10];
    const float* W3  = (const float*)d_in[11];
    const float* as3 = (const float*)d_in[12];
    const float* ad3 = (const float*)d_in[13];
    const float* b3  = (const float*)d_in[14];
    const float* Wl  = (const float*)d_in[15];
    const float* bl  = (const float*)d_in[16];
    float* out = (float*)d_out;

    char* ws = (char*)d_ws;
    size_t p = 0;
    auto alloc = [&](size_t bytes) {
        size_t a = p;
        p += (bytes + 255) & ~(size_t)255;
        return a;
    };
    int*      off  = (int*)(ws + alloc((NNODES + 1) * 4));
    int*      deg  = (int*)(ws + alloc((size_t)NNODES * 4));
    int*      bcur = (int*)(ws + alloc(256 * 4));
    int*      ssrc = (int*)(ws + alloc((size_t)ETOT * 4));
    unsigned* tmp  = (unsigned*)(ws + alloc((size_t)ETOT * 4));
    int*      bsum = (int*)(ws + alloc(256 * 4));
    float*    es   = (float*)(ws + alloc((size_t)NNODES * NHEAD * 4));
    float*    ed   = (float*)(ws + alloc((size_t)NNODES * NHEAD * 4));
    u16*      xb   = (u16*)(ws + alloc((size_t)NNODES * FIN * 2));
    u16*      w1b  = (u16*)(ws + alloc((size_t)HC * FIN * 2));
    u16*      w2b  = (u16*)(ws + alloc((size_t)HC * HC * 2));
    u16*      w3b  = (u16*)(ws + alloc((size_t)HC * HC * 2));
    u8*       Hb   = (u8*)(ws + alloc((size_t)NNODES * HC));       // fp8 e4m3, σ-layout
    u16*      Ab   = (u16*)(ws + alloc((size_t)NNODES * HC * 2));  // bf16, σ-layout
    float*    pp   = (float*)(ws + alloc((size_t)NGRAPH * 8 * HC * 4));   // pool partials
    int*      goff = (int*)(ws + alloc((size_t)(NGRAPH + 1) * 4));
    alloc(128 * 1024);   // slack: gemm A-tile over-read past row NNODES stays in d_ws

    // zero deg+bcur (contiguous)
    hipMemsetAsync(deg, 0, (size_t)((char*)ssrc - (char*)deg), stream);

    // conversions + degree histogram (one fused kernel)
    prep_kernel<<<NBCONV + NBDEG, 256, 0, stream>>>(x, W1, W2, W3, xb, w1b, w2b, w3b, ei, deg);

    // counting sort of edges by dst (two-pass, block-aggregated atomics)
    scan1_kernel<<<NB196, 256, 0, stream>>>(deg, off, bsum);
    scan2_kernel<<<1, 256, 0, stream>>>(bsum, bat, goff);
    scatter1_kernel<<<NBS1, 256, 0, stream>>>(ei, bsum, bcur, tmp);
    scatter2_kernel<<<NB196, 256, 0, stream>>>(tmp, off, bsum, ssrc);

    dim3 ggrid((NNODES + TBM - 1) / TBM, HC / TBN);
    int nblocks4 = (NNODES + 3) / 4;

    // layer 1
    gemm_mfma<<<ggrid, 256, 0, stream>>>(xb, w1b, Hb, FIN, as1, ad1, es, ed);
    aggregate_kernel<<<nblocks4, 256, 0, stream>>>(Hb, ssrc, off, bsum, es, ed, b1, Ab, 1);
    // layer 2
    gemm_mfma<<<ggrid, 256, 0, stream>>>(Ab, w2b, Hb, HC, as2, ad2, es, ed);
    aggregate_kernel<<<nblocks4, 256, 0, stream>>>(Hb, ssrc, off, bsum, es, ed, b2, Ab, 1);
    // layer 3
    gemm_mfma<<<ggrid, 256, 0, stream>>>(Ab, w3b, Hb, HC, as3, ad3, es, ed);
    aggregate_kernel<<<nblocks4, 256, 0, stream>>>(Hb, ssrc, off, bsum, es, ed, b3, Ab, 0);

    // pool + classify
    dim3 pgrid(NGRAPH, 8);
    pool_kernel<<<pgrid, 256, 0, stream>>>(Ab, goff, pp);
    final_kernel<<<NGRAPH, 64, 0, stream>>>(pp, goff, Wl, bl, out);
}